// Round 1
// baseline (819.972 us; speedup 1.0000x reference)
//
#include <hip/hip_runtime.h>
#include <hip/hip_fp16.h>

// R1: kill the scatter write-amplification.
// Old k_scatter_cap: 2M random 4B stores into a 38.4MB per-node CAP-CSR ->
// every store its own 64B line writeback (WRITE_SIZE 122MB, 1.1TB/s, 120us).
// New pipeline:
//   k_bin: ticket-scatter (v-node, rel) into 782 coarse buckets of VNB=256
//     v-nodes (v = 2h / 2t+1 interleaved so both sides of a node share a
//     bucket). Consecutive tickets -> consecutive addresses -> L2 lines fill
//     within a short window and write back ~once (payload 8MB dense-ish).
//     z is NOT stored: for fixed node, z = exp(lrelu(e_node + er[r])) depends
//     only on r, so the consumer recomputes it at full f32.
//   k_group_out: one block per coarse bucket. Entries -> registers (static
//     KPT slots, no dynamic indexing), LDS histogram -> scan -> LDS
//     counting-sort into per-node CSR (2B rel), then the proven table-MAC
//     inner loop per node straight from LDS; writes out rows. No CAP-CSR
//     round-trip through HBM at all.
// NOTE: all scatter stores remain PLAIN stores (nontemporal broke coherence
// with harness poison-writes in a previous session).

#define VNB   256                 // v-nodes per coarse bucket (=128 e-nodes)
#define VSH   8                   // log2(VNB)
#define KPT   14                  // staged entries per thread in k_group_out
#define BCAP  (KPT * 256)         // 3584 = mean 2560 + ~20 sigma (Poisson)
#define MAXD  64                  // per-node degree cap in output stage

// K1: eh[n]=x_e[n]·w_ah, et[n]=x_e[n]·w_at; er[r]=x_r[r]·w_ar. One wave/row.
__global__ __launch_bounds__(256) void k_scores(
    const float* __restrict__ xe, const float* __restrict__ xr,
    const float* __restrict__ wah, const float* __restrict__ wat, const float* __restrict__ war,
    float* __restrict__ eh, float* __restrict__ et, float* __restrict__ er,
    int nE, int nR) {
    int wid = (blockIdx.x * blockDim.x + threadIdx.x) >> 6;
    int lane = threadIdx.x & 63;
    if (wid < nE) {
        float2 x2 = *(const float2*)(xe + (size_t)wid * 128 + lane * 2);
        float2 a2 = *(const float2*)(wah + lane * 2);
        float2 b2 = *(const float2*)(wat + lane * 2);
        float dh = x2.x * a2.x + x2.y * a2.y;
        float dt = x2.x * b2.x + x2.y * b2.y;
        #pragma unroll
        for (int m = 32; m >= 1; m >>= 1) { dh += __shfl_xor(dh, m); dt += __shfl_xor(dt, m); }
        if (lane == 0) { eh[wid] = dh; et[wid] = dt; }
    } else if (wid < nE + nR) {
        int r = wid - nE;
        float2 x2 = *(const float2*)(xr + (size_t)r * 128 + lane * 2);
        float2 c2 = *(const float2*)(war + lane * 2);
        float d = x2.x * c2.x + x2.y * c2.y;
        #pragma unroll
        for (int m = 32; m >= 1; m >>= 1) d += __shfl_xor(d, m);
        if (lane == 0) er[r] = d;
    }
}

// K2: fused relation pipeline (1 block/relation, 256 thr):
//   hidden = x_r@W1+b1 ; msg = x_r + hidden@W2+b2 ; Mh/Mt = msg@Wr halves (fp16)
__global__ __launch_bounds__(256) void k_rel(
    const float* __restrict__ xr,
    const float* __restrict__ W1, const float* __restrict__ b1,
    const float* __restrict__ W2, const float* __restrict__ b2,
    const float* __restrict__ Wr,
    __half* __restrict__ Mh, __half* __restrict__ Mt) {
    __shared__ float xs[128];
    __shared__ float hs[256];
    __shared__ float ms[128];
    int r = blockIdx.x, j = threadIdx.x;
    if (j < 128) xs[j] = xr[(size_t)r * 128 + j];
    __syncthreads();
    {
        float acc = b1[j];
        #pragma unroll 4
        for (int k = 0; k < 128; ++k) acc += xs[k] * W1[k * 256 + j];
        hs[j] = acc;
    }
    __syncthreads();
    if (j < 128) {
        float acc = b2[j] + xs[j];
        #pragma unroll 4
        for (int k = 0; k < 256; ++k) acc += hs[k] * W2[k * 128 + j];
        ms[j] = acc;
    }
    __syncthreads();
    {
        float ah = 0.f, at_ = 0.f;
        #pragma unroll 4
        for (int i = 0; i < 128; ++i) {
            float m = ms[i];
            ah  += m * Wr[i * 256 + j];
            at_ += m * Wr[(128 + i) * 256 + j];
        }
        Mh[(size_t)r * 256 + j] = __float2half(ah);
        Mt[(size_t)r * 256 + j] = __float2half(at_);
    }
}

// K3: coarse binning. Entry = (v & (VNB-1)) << 10 | rel  (18 bits used).
// No eh/et/er reads, no exp: shortest possible dependency chain, and ticket
// adjacency packs consecutive stores into the same cache lines.
__global__ __launch_bounds__(256) void k_bin(
    const int* __restrict__ ei, const int* __restrict__ rel,
    int* __restrict__ bcur, unsigned* __restrict__ coarse, int E) {
    int e = blockIdx.x * blockDim.x + threadIdx.x;
    if (e >= E) return;
    unsigned h = (unsigned)ei[e], t = (unsigned)ei[E + e], r = (unsigned)rel[e];
    unsigned vh = h << 1;          // head side: v = 2h
    unsigned vt = (t << 1) | 1u;   // tail side: v = 2t+1
    int bh = vh >> VSH, bt = vt >> VSH;
    int ph = atomicAdd(&bcur[bh], 1);
    if (ph < BCAP) coarse[(size_t)bh * BCAP + ph] = ((vh & (VNB - 1u)) << 10) | r;
    int pt = atomicAdd(&bcur[bt], 1);
    if (pt < BCAP) coarse[(size_t)bt * BCAP + pt] = ((vt & (VNB - 1u)) << 10) | r;
}

// K4: fused group + output. One block per coarse bucket (256 thr, 4 waves).
//   phase 1: entries -> registers (static slots) + LDS histogram
//   phase 2: 256-wide scan -> per-node offsets
//   phase 3: counting-sort rels into LDS CSR (atomic ticket per node)
//   phase 4: wave per e-node: recompute z at f32, pack (z22|rel10) like the
//            old CSR entry, and run the proven shfl-broadcast table-MAC loop.
__global__ __launch_bounds__(256) void k_group_out(
    const int* __restrict__ bcur, const unsigned* __restrict__ coarse,
    const float* __restrict__ eh, const float* __restrict__ et, const float* __restrict__ er,
    const __half* __restrict__ Mh, const __half* __restrict__ Mt,
    const float* __restrict__ br, float* __restrict__ out, int nE) {
    __shared__ unsigned short csr[BCAP];
    __shared__ int cnt[VNB];
    __shared__ int offs[VNB];
    __shared__ int wt[4];
    int b = blockIdx.x, tid = threadIdx.x;
    int cn = min(bcur[b], BCAP);
    cnt[tid] = 0;
    __syncthreads();
    const unsigned* src = coarse + (size_t)b * BCAP;
    unsigned ent[KPT];
    #pragma unroll
    for (int k = 0; k < KPT; ++k) {
        int i = tid + k * 256;
        unsigned v = 0xFFFFFFFFu;              // sentinel (real entries < 2^18)
        if (i < cn) { v = src[i]; atomicAdd(&cnt[v >> 10], 1); }
        ent[k] = v;
    }
    __syncthreads();
    int lane = tid & 63, wid = tid >> 6;
    {   // exclusive scan of 256 counts (4 waves x 64-lane shfl scan)
        int v = cnt[tid];
        int incl = v;
        #pragma unroll
        for (int d = 1; d < 64; d <<= 1) { int u = __shfl_up(incl, d); if (lane >= d) incl += u; }
        if (lane == 63) wt[wid] = incl;
        __syncthreads();
        int base = 0;
        for (int w = 0; w < wid; ++w) base += wt[w];
        offs[tid] = base + incl - v;
    }
    __syncthreads();
    cnt[tid] = offs[tid];     // cnt becomes the scatter cursor
    __syncthreads();
    #pragma unroll
    for (int k = 0; k < KPT; ++k) {
        unsigned v = ent[k];
        if (v != 0xFFFFFFFFu) {
            int p = atomicAdd(&cnt[v >> 10], 1);
            csr[p] = (unsigned short)(v & 1023u);
        }
    }
    __syncthreads();          // after this, cnt[v] = end offset of node v
    float4 bv = *(const float4*)(br + lane * 4);
    int nbase = b * (VNB / 2);
    for (int li = wid; li < VNB / 2; li += 4) {
        int n = nbase + li;
        if (n >= nE) break;
        int oH = offs[2 * li],     eHend = cnt[2 * li];
        int oT = offs[2 * li + 1], eTend = cnt[2 * li + 1];
        int dH = min(eHend - oH, MAXD);
        int dT = min(eTend - oT, MAXD);
        float ehn = eh[n], etn = et[n];
        unsigned eHv = 0u, eTv = 0u;
        if (lane < dH) {
            int r = csr[oH + lane];
            float l = ehn + er[r]; l = l > 0.f ? l : 0.01f * l;
            eHv = (__float_as_uint(__expf(l)) & 0xFFFFFC00u) | (unsigned)r;
        }
        if (lane < dT) {
            int r = csr[oT + lane];
            float l = etn + er[r]; l = l > 0.f ? l : 0.01f * l;
            eTv = (__float_as_uint(__expf(l)) & 0xFFFFFC00u) | (unsigned)r;
        }
        float4 accH = {0, 0, 0, 0}, accT = {0, 0, 0, 0};
        float sH = 0.f, sT = 0.f;
        int kk = max(dH, dT);   // <= MAXD=64: j+3 <= 63, shfl always in range
        for (int j = 0; j < kk; j += 4) {
            unsigned cH[4], cT[4];
            #pragma unroll
            for (int i = 0; i < 4; ++i) {
                cH[i] = (unsigned)__shfl((int)eHv, j + i);
                cT[i] = (unsigned)__shfl((int)eTv, j + i);
            }
            uint2 mH[4], mT[4];
            #pragma unroll
            for (int i = 0; i < 4; ++i) {
                mH[i] = *(const uint2*)(Mh + (((size_t)(cH[i] & 0x3FFu)) << 8) + (lane << 2));
                mT[i] = *(const uint2*)(Mt + (((size_t)(cT[i] & 0x3FFu)) << 8) + (lane << 2));
            }
            #pragma unroll
            for (int i = 0; i < 4; ++i) {
                float zH = __uint_as_float(cH[i] & 0xFFFFFC00u);
                float zT = __uint_as_float(cT[i] & 0xFFFFFC00u);
                float2 h01 = __half22float2(*(const __half2*)&mH[i].x);
                float2 h23 = __half22float2(*(const __half2*)&mH[i].y);
                float2 t01 = __half22float2(*(const __half2*)&mT[i].x);
                float2 t23 = __half22float2(*(const __half2*)&mT[i].y);
                accH.x += zH * h01.x; accH.y += zH * h01.y;
                accH.z += zH * h23.x; accH.w += zH * h23.y;
                accT.x += zT * t01.x; accT.y += zT * t01.y;
                accT.z += zT * t23.x; accT.w += zT * t23.y;
                sH += zH; sT += zT;
            }
        }
        float iH = 1.f / (sH + 1e-16f);
        float iT = 1.f / (sT + 1e-16f);
        float4 o;
        o.x = accH.x * iH + accT.x * iT + bv.x;
        o.y = accH.y * iH + accT.y * iT + bv.y;
        o.z = accH.z * iH + accT.z * iT + bv.z;
        o.w = accH.w * iH + accT.w * iT + bv.w;
        *(float4*)(out + (size_t)n * 256 + lane * 4) = o;
    }
}

// ---- Plan A fallback (ws too small): hist + scan + offset CSR ----
__global__ __launch_bounds__(256) void k_hist(
    const int* __restrict__ ei, int* __restrict__ deg, int E, int nE) {
    int e = blockIdx.x * blockDim.x + threadIdx.x;
    if (e >= E) return;
    atomicAdd(&deg[ei[e]], 1);
    atomicAdd(&deg[nE + ei[E + e]], 1);
}

__global__ __launch_bounds__(256) void k_scan1(
    const int* __restrict__ deg, int* __restrict__ offs, int* __restrict__ bsum, int N) {
    __shared__ int wtot[4];
    int tid = threadIdx.x, lane = tid & 63, wid = tid >> 6;
    int base = blockIdx.x * 1024 + tid * 4;
    int v[4];
    #pragma unroll
    for (int i = 0; i < 4; ++i) v[i] = (base + i < N) ? deg[base + i] : 0;
    int ts = v[0] + v[1] + v[2] + v[3];
    int incl = ts;
    #pragma unroll
    for (int d = 1; d < 64; d <<= 1) { int u = __shfl_up(incl, d); if (lane >= d) incl += u; }
    if (lane == 63) wtot[wid] = incl;
    __syncthreads();
    int wbase = 0;
    for (int w = 0; w < wid; ++w) wbase += wtot[w];
    int run = wbase + incl - ts;
    #pragma unroll
    for (int i = 0; i < 4; ++i) { if (base + i < N) offs[base + i] = run; run += v[i]; }
    if (tid == 255) bsum[blockIdx.x] = wbase + incl;
}

__global__ __launch_bounds__(256) void k_scan2(int* __restrict__ bsum, int NB) {
    __shared__ int wtot[4];
    int tid = threadIdx.x, lane = tid & 63, wid = tid >> 6;
    int v = (tid < NB) ? bsum[tid] : 0;
    int incl = v;
    #pragma unroll
    for (int d = 1; d < 64; d <<= 1) { int u = __shfl_up(incl, d); if (lane >= d) incl += u; }
    if (lane == 63) wtot[wid] = incl;
    __syncthreads();
    int wbase = 0;
    for (int w = 0; w < wid; ++w) wbase += wtot[w];
    if (tid < NB) bsum[tid] = wbase + incl - v;
}

__global__ __launch_bounds__(256) void k_scan3(
    int* __restrict__ offs, const int* __restrict__ bsum, int* __restrict__ cursor, int N) {
    int i = blockIdx.x * blockDim.x + threadIdx.x;
    if (i >= N) return;
    int v = offs[i] + bsum[i >> 10];
    offs[i] = v;
    cursor[i] = v;
}

__global__ __launch_bounds__(256) void k_scatter_offs(
    const int* __restrict__ ei, const int* __restrict__ rel,
    const float* __restrict__ eh, const float* __restrict__ et, const float* __restrict__ er,
    int* __restrict__ cursor, unsigned* __restrict__ csr, int E, int nE) {
    int e = blockIdx.x * blockDim.x + threadIdx.x;
    if (e >= E) return;
    int h = ei[e], t = ei[E + e], r = rel[e];
    float erv = er[r];
    float lh = eh[h] + erv; lh = lh > 0.f ? lh : 0.01f * lh;
    float lt = et[t] + erv; lt = lt > 0.f ? lt : 0.01f * lt;
    unsigned zh = (__float_as_uint(__expf(lh)) & 0xFFFFFC00u) | (unsigned)r;
    unsigned zt = (__float_as_uint(__expf(lt)) & 0xFFFFFC00u) | (unsigned)r;
    int ph = atomicAdd(&cursor[h], 1);
    csr[ph] = zh;
    int pt = atomicAdd(&cursor[nE + t], 1);
    csr[pt] = zt;
}

__global__ __launch_bounds__(256) void k_out_offs(
    const int* __restrict__ offs, const int* __restrict__ deg, const unsigned* __restrict__ csr,
    const __half* __restrict__ Mh, const __half* __restrict__ Mt, const float* __restrict__ br,
    float* __restrict__ out, int nE) {
    int wid = (blockIdx.x * blockDim.x + threadIdx.x) >> 6;
    int lane = threadIdx.x & 63;
    if (wid >= nE) return;
    int dH = deg[wid], dT = deg[nE + wid];
    size_t offH = (size_t)offs[wid], offT = (size_t)offs[nE + wid];
    float4 accH = {0, 0, 0, 0}, accT = {0, 0, 0, 0};
    float sH = 0.f, sT = 0.f;
    int dM = max(dH, dT);
    for (int b = 0; b < dM; b += 64) {
        int kH = min(64, dH - b);
        int kT = min(64, dT - b);
        unsigned eH = 0, eT = 0;
        if (lane < kH) eH = csr[offH + b + lane];
        if (lane < kT) eT = csr[offT + b + lane];
        int kk = max(kH, kT);
        for (int j = 0; j < kk; ++j) {
            unsigned cH = (unsigned)__shfl((int)eH, j);
            unsigned cT = (unsigned)__shfl((int)eT, j);
            if (j < kH) {
                float z = __uint_as_float(cH & 0xFFFFFC00u);
                int r = (int)(cH & 0x3FFu);
                const __half2* mp = (const __half2*)(Mh + ((size_t)r << 8) + (lane << 2));
                float2 m01 = __half22float2(mp[0]);
                float2 m23 = __half22float2(mp[1]);
                accH.x += z * m01.x; accH.y += z * m01.y;
                accH.z += z * m23.x; accH.w += z * m23.y;
                sH += z;
            }
            if (j < kT) {
                float z = __uint_as_float(cT & 0xFFFFFC00u);
                int r = (int)(cT & 0x3FFu);
                const __half2* mp = (const __half2*)(Mt + ((size_t)r << 8) + (lane << 2));
                float2 m01 = __half22float2(mp[0]);
                float2 m23 = __half22float2(mp[1]);
                accT.x += z * m01.x; accT.y += z * m01.y;
                accT.z += z * m23.x; accT.w += z * m23.y;
                sT += z;
            }
        }
    }
    float iH = 1.f / (sH + 1e-16f);
    float iT = 1.f / (sT + 1e-16f);
    float4 bv = *(const float4*)(br + lane * 4);
    float4 o;
    o.x = accH.x * iH + accT.x * iT + bv.x;
    o.y = accH.y * iH + accT.y * iT + bv.y;
    o.z = accH.z * iH + accT.z * iT + bv.z;
    o.w = accH.w * iH + accT.w * iT + bv.w;
    *(float4*)(out + (size_t)wid * 256 + lane * 4) = o;
}

extern "C" void kernel_launch(void* const* d_in, const int* in_sizes, int n_in,
                              void* d_out, int out_size, void* d_ws, size_t ws_size,
                              hipStream_t stream) {
    const float* xe  = (const float*)d_in[0];
    const float* xr  = (const float*)d_in[1];
    const int*   ei  = (const int*)d_in[2];
    const int*   rel = (const int*)d_in[3];
    const float* wah = (const float*)d_in[5];
    const float* wat = (const float*)d_in[6];
    const float* war = (const float*)d_in[7];
    const float* W1  = (const float*)d_in[8];
    const float* b1  = (const float*)d_in[9];
    const float* W2  = (const float*)d_in[10];
    const float* b2  = (const float*)d_in[11];
    const float* Wr  = (const float*)d_in[12];
    const float* br  = (const float*)d_in[13];
    float* out = (float*)d_out;

    const int nE = in_sizes[0] / 128;   // 100000
    const int nR = in_sizes[1] / 128;   // 1000
    const int E  = in_sizes[3];         // 1000000
    const int N  = 2 * nE;
    const int NBUCK = (N + VNB - 1) >> VSH;   // 782 coarse buckets

    float* ws = (float*)d_ws;
    size_t o = 0;
    auto alloc = [&](size_t words) { size_t r = o; o += (words + 3) & ~(size_t)3; return r; };
    float* eh     = ws + alloc(nE);
    float* et     = ws + alloc(nE);
    float* er     = ws + alloc(nR);
    __half* Mh    = (__half*)(ws + alloc((size_t)nR * 128));   // nR*256 halves
    __half* Mt    = (__half*)(ws + alloc((size_t)nR * 128));
    int*   bcur   = (int*)(ws + alloc(NBUCK));
    size_t common_words = o;

    bool planNew = (ws_size >= (common_words + (size_t)NBUCK * BCAP + 64) * 4);

    k_scores<<<(nE + nR + 3) / 4, 256, 0, stream>>>(xe, xr, wah, wat, war, eh, et, er, nE, nR);
    k_rel<<<nR, 256, 0, stream>>>(xr, W1, b1, W2, b2, Wr, Mh, Mt);

    if (planNew) {
        unsigned* coarse = (unsigned*)(ws + alloc((size_t)NBUCK * BCAP));
        hipMemsetAsync(bcur, 0, (size_t)NBUCK * sizeof(int), stream);
        k_bin<<<(E + 255) / 256, 256, 0, stream>>>(ei, rel, bcur, coarse, E);
        k_group_out<<<NBUCK, 256, 0, stream>>>(bcur, coarse, eh, et, er, Mh, Mt, br, out, nE);
    } else {
        int* cursor = (int*)(ws + alloc(N));
        int* deg    = (int*)(ws + alloc(N));
        int* offs   = (int*)(ws + alloc(N));
        int* bsum   = (int*)(ws + alloc(512));
        unsigned* csr = (unsigned*)(ws + alloc(2 * (size_t)E));
        const int NB = (N + 1023) / 1024;
        hipMemsetAsync(deg, 0, (size_t)N * sizeof(int), stream);
        k_hist<<<(E + 255) / 256, 256, 0, stream>>>(ei, deg, E, nE);
        k_scan1<<<NB, 256, 0, stream>>>(deg, offs, bsum, N);
        k_scan2<<<1, 256, 0, stream>>>(bsum, NB);
        k_scan3<<<(N + 255) / 256, 256, 0, stream>>>(offs, bsum, cursor, N);
        k_scatter_offs<<<(E + 255) / 256, 256, 0, stream>>>(ei, rel, eh, et, er, cursor, csr, E, nE);
        k_out_offs<<<(nE + 3) / 4, 256, 0, stream>>>(offs, deg, csr, Mh, Mt, br, out, nE);
    }
}

// Round 3
// 424.168 us; speedup vs baseline: 1.9331x; 1.9331x over previous
//
#include <hip/hip_runtime.h>
#include <hip/hip_fp16.h>

// R3 = R2 resubmission (R2 bench died at the container level with no pytest
// error; audit found no OOB/hang candidates -> infra flake assumed).
// Design (from R1 post-mortem):
//   R1's k_bin had 782 cursors for 2M device atomics = 2560/address; measured
//   ~183ns per serialized same-address atomic -> 470us at 202GB/s, VALU 0.1%.
//   WRITE_SIZE 87MB ~= 8 XCDs x 11MB buffer: cross-XCD line sharing is the
//   writeback amplifier (R0: 2M temporally-spread 4B stores -> 122MB, i.e.
//   one 64B line writeback per store).
// R3 rules:
//   (1) >= ~10K atomic counters so fan-in per address <= ~100.
//   (2) single-XCD-writer lines: segment select = blockIdx.x & 7 (~XCD id),
//       so dirty lines merge in that XCD's L2 and write back ~once.
// k_bin2: buckets of VNB2=64 v-nodes (32 e-nodes), 8 segments/bucket.
//   entry = 16-bit: local_v(6) << 10 | rel(10). 3125 buckets x 8 segs = 25K
//   counters (fan-in ~80). Segment cap 160 (mean 80, +9 sigma). Buffer 8MB.
//   z is NOT stored: z = exp(lrelu(e_node + er[r])) depends only on (node,r),
//   consumer recomputes at full f32.
// k_group_out2: one block/bucket (3125 blocks, 256 thr). Merge 8 segments in
//   LDS: histogram -> 64-bin scan -> counting sort -> per-node CSR (rel only);
//   then the proven shfl-broadcast table-MAC loop; 32 e-nodes/block.
// NOTE: all scatter stores remain PLAIN stores (nontemporal broke coherence
// with harness poison-writes in a previous session).

#define VNB2  64                  // v-nodes per bucket (32 e-nodes)
#define VSH2  6
#define SEG   8                   // segments per bucket (~per-XCD)
#define SCAP  160                 // entries per segment (mean 80)
#define MAXD  64                  // per-node degree cap in output stage

// K1: eh[n]=x_e[n]·w_ah, et[n]=x_e[n]·w_at; er[r]=x_r[r]·w_ar. One wave/row.
__global__ __launch_bounds__(256) void k_scores(
    const float* __restrict__ xe, const float* __restrict__ xr,
    const float* __restrict__ wah, const float* __restrict__ wat, const float* __restrict__ war,
    float* __restrict__ eh, float* __restrict__ et, float* __restrict__ er,
    int nE, int nR) {
    int wid = (blockIdx.x * blockDim.x + threadIdx.x) >> 6;
    int lane = threadIdx.x & 63;
    if (wid < nE) {
        float2 x2 = *(const float2*)(xe + (size_t)wid * 128 + lane * 2);
        float2 a2 = *(const float2*)(wah + lane * 2);
        float2 b2 = *(const float2*)(wat + lane * 2);
        float dh = x2.x * a2.x + x2.y * a2.y;
        float dt = x2.x * b2.x + x2.y * b2.y;
        #pragma unroll
        for (int m = 32; m >= 1; m >>= 1) { dh += __shfl_xor(dh, m); dt += __shfl_xor(dt, m); }
        if (lane == 0) { eh[wid] = dh; et[wid] = dt; }
    } else if (wid < nE + nR) {
        int r = wid - nE;
        float2 x2 = *(const float2*)(xr + (size_t)r * 128 + lane * 2);
        float2 c2 = *(const float2*)(war + lane * 2);
        float d = x2.x * c2.x + x2.y * c2.y;
        #pragma unroll
        for (int m = 32; m >= 1; m >>= 1) d += __shfl_xor(d, m);
        if (lane == 0) er[r] = d;
    }
}

// K2: fused relation pipeline (1 block/relation, 256 thr):
//   hidden = x_r@W1+b1 ; msg = x_r + hidden@W2+b2 ; Mh/Mt = msg@Wr halves (fp16)
__global__ __launch_bounds__(256) void k_rel(
    const float* __restrict__ xr,
    const float* __restrict__ W1, const float* __restrict__ b1,
    const float* __restrict__ W2, const float* __restrict__ b2,
    const float* __restrict__ Wr,
    __half* __restrict__ Mh, __half* __restrict__ Mt) {
    __shared__ float xs[128];
    __shared__ float hs[256];
    __shared__ float ms[128];
    int r = blockIdx.x, j = threadIdx.x;
    if (j < 128) xs[j] = xr[(size_t)r * 128 + j];
    __syncthreads();
    {
        float acc = b1[j];
        #pragma unroll 4
        for (int k = 0; k < 128; ++k) acc += xs[k] * W1[k * 256 + j];
        hs[j] = acc;
    }
    __syncthreads();
    if (j < 128) {
        float acc = b2[j] + xs[j];
        #pragma unroll 4
        for (int k = 0; k < 256; ++k) acc += hs[k] * W2[k * 128 + j];
        ms[j] = acc;
    }
    __syncthreads();
    {
        float ah = 0.f, at_ = 0.f;
        #pragma unroll 4
        for (int i = 0; i < 128; ++i) {
            float m = ms[i];
            ah  += m * Wr[i * 256 + j];
            at_ += m * Wr[(128 + i) * 256 + j];
        }
        Mh[(size_t)r * 256 + j] = __float2half(ah);
        Mt[(size_t)r * 256 + j] = __float2half(at_);
    }
}

// K3: segmented coarse binning. 25K counters (fan-in ~80/address); segment
// chosen by blockIdx&7 so each segment's lines have a single XCD writer.
__global__ __launch_bounds__(256) void k_bin2(
    const int* __restrict__ ei, const int* __restrict__ rel,
    int* __restrict__ bcur, unsigned short* __restrict__ coarse, int E) {
    int e = blockIdx.x * blockDim.x + threadIdx.x;
    if (e >= E) return;
    int s = blockIdx.x & (SEG - 1);
    unsigned h = (unsigned)ei[e], t = (unsigned)ei[E + e], r = (unsigned)rel[e];
    unsigned vh = h << 1;          // head side: v = 2h
    unsigned vt = (t << 1) | 1u;   // tail side: v = 2t+1
    unsigned bh = vh >> VSH2, bt = vt >> VSH2;
    unsigned short evh = (unsigned short)(((vh & (VNB2 - 1u)) << 10) | r);
    unsigned short evt = (unsigned short)(((vt & (VNB2 - 1u)) << 10) | r);
    int ph = atomicAdd(&bcur[bh * SEG + s], 1);
    if (ph < SCAP) coarse[((size_t)bh * SEG + s) * SCAP + ph] = evh;
    int pt = atomicAdd(&bcur[bt * SEG + s], 1);
    if (pt < SCAP) coarse[((size_t)bt * SEG + s) * SCAP + pt] = evt;
}

// K4: fused group + output. One block per bucket (256 thr, 4 waves).
//   phase 1: copy 8 segments' valid prefixes to LDS + histogram (64 bins)
//   phase 2: 64-bin scan (wave 0)
//   phase 3: LDS counting-sort rels into per-node CSR
//   phase 4: wave handles 8 e-nodes: recompute z at f32, pack (z22|rel10),
//            proven shfl-broadcast table-MAC loop, write out row.
__global__ __launch_bounds__(256) void k_group_out2(
    const int* __restrict__ bcur, const unsigned short* __restrict__ coarse,
    const float* __restrict__ eh, const float* __restrict__ et, const float* __restrict__ er,
    const __half* __restrict__ Mh, const __half* __restrict__ Mt,
    const float* __restrict__ br, float* __restrict__ out, int nE) {
    __shared__ unsigned short ent[SEG][SCAP];      // 2560 B
    __shared__ unsigned short csr[SEG * SCAP];     // 2560 B
    __shared__ int cnt[VNB2], offs[VNB2], cur[VNB2];
    __shared__ int segc[SEG];
    int b = blockIdx.x, tid = threadIdx.x;
    if (tid < VNB2) cnt[tid] = 0;
    if (tid < SEG) segc[tid] = min(bcur[b * SEG + tid], SCAP);
    __syncthreads();
    const unsigned short* src = coarse + (size_t)b * SEG * SCAP;
    for (int s = 0; s < SEG; ++s) {
        int c = segc[s];
        for (int i = tid; i < c; i += 256) {
            unsigned short v = src[s * SCAP + i];
            ent[s][i] = v;
            atomicAdd(&cnt[v >> 10], 1);
        }
    }
    __syncthreads();
    if (tid < 64) {   // wave 0: inclusive shfl scan over 64 bins -> exclusive
        int v = cnt[tid];
        int incl = v;
        #pragma unroll
        for (int d = 1; d < 64; d <<= 1) { int u = __shfl_up(incl, d); if (tid >= d) incl += u; }
        offs[tid] = incl - v;
        cur[tid] = incl - v;
    }
    __syncthreads();
    for (int s = 0; s < SEG; ++s) {
        int c = segc[s];
        for (int i = tid; i < c; i += 256) {
            unsigned short v = ent[s][i];
            int p = atomicAdd(&cur[v >> 10], 1);
            csr[p] = (unsigned short)(v & 1023u);
        }
    }
    __syncthreads();          // after this, cur[v] = end offset of node v
    int lane = tid & 63, wid = tid >> 6;
    float4 bv = *(const float4*)(br + lane * 4);
    int nbase = b * (VNB2 / 2);
    for (int li = wid; li < VNB2 / 2; li += 4) {
        int n = nbase + li;
        if (n >= nE) break;
        int oH = offs[2 * li],     eHend = cur[2 * li];
        int oT = offs[2 * li + 1], eTend = cur[2 * li + 1];
        int dH = min(eHend - oH, MAXD);
        int dT = min(eTend - oT, MAXD);
        float ehn = eh[n], etn = et[n];
        unsigned eHv = 0u, eTv = 0u;
        if (lane < dH) {
            int r = csr[oH + lane];
            float l = ehn + er[r]; l = l > 0.f ? l : 0.01f * l;
            eHv = (__float_as_uint(__expf(l)) & 0xFFFFFC00u) | (unsigned)r;
        }
        if (lane < dT) {
            int r = csr[oT + lane];
            float l = etn + er[r]; l = l > 0.f ? l : 0.01f * l;
            eTv = (__float_as_uint(__expf(l)) & 0xFFFFFC00u) | (unsigned)r;
        }
        float4 accH = {0, 0, 0, 0}, accT = {0, 0, 0, 0};
        float sH = 0.f, sT = 0.f;
        int kk = max(dH, dT);   // <= MAXD=64: j+3 <= 63, shfl always in range
        for (int j = 0; j < kk; j += 4) {
            unsigned cH[4], cT[4];
            #pragma unroll
            for (int i = 0; i < 4; ++i) {
                cH[i] = (unsigned)__shfl((int)eHv, j + i);
                cT[i] = (unsigned)__shfl((int)eTv, j + i);
            }
            uint2 mH[4], mT[4];
            #pragma unroll
            for (int i = 0; i < 4; ++i) {
                mH[i] = *(const uint2*)(Mh + (((size_t)(cH[i] & 0x3FFu)) << 8) + (lane << 2));
                mT[i] = *(const uint2*)(Mt + (((size_t)(cT[i] & 0x3FFu)) << 8) + (lane << 2));
            }
            #pragma unroll
            for (int i = 0; i < 4; ++i) {
                float zH = __uint_as_float(cH[i] & 0xFFFFFC00u);
                float zT = __uint_as_float(cT[i] & 0xFFFFFC00u);
                float2 h01 = __half22float2(*(const __half2*)&mH[i].x);
                float2 h23 = __half22float2(*(const __half2*)&mH[i].y);
                float2 t01 = __half22float2(*(const __half2*)&mT[i].x);
                float2 t23 = __half22float2(*(const __half2*)&mT[i].y);
                accH.x += zH * h01.x; accH.y += zH * h01.y;
                accH.z += zH * h23.x; accH.w += zH * h23.y;
                accT.x += zT * t01.x; accT.y += zT * t01.y;
                accT.z += zT * t23.x; accT.w += zT * t23.y;
                sH += zH; sT += zT;
            }
        }
        float iH = 1.f / (sH + 1e-16f);
        float iT = 1.f / (sT + 1e-16f);
        float4 o;
        o.x = accH.x * iH + accT.x * iT + bv.x;
        o.y = accH.y * iH + accT.y * iT + bv.y;
        o.z = accH.z * iH + accT.z * iT + bv.z;
        o.w = accH.w * iH + accT.w * iT + bv.w;
        *(float4*)(out + (size_t)n * 256 + lane * 4) = o;
    }
}

// ---- Plan A fallback (ws too small): hist + scan + offset CSR ----
__global__ __launch_bounds__(256) void k_hist(
    const int* __restrict__ ei, int* __restrict__ deg, int E, int nE) {
    int e = blockIdx.x * blockDim.x + threadIdx.x;
    if (e >= E) return;
    atomicAdd(&deg[ei[e]], 1);
    atomicAdd(&deg[nE + ei[E + e]], 1);
}

__global__ __launch_bounds__(256) void k_scan1(
    const int* __restrict__ deg, int* __restrict__ offs, int* __restrict__ bsum, int N) {
    __shared__ int wtot[4];
    int tid = threadIdx.x, lane = tid & 63, wid = tid >> 6;
    int base = blockIdx.x * 1024 + tid * 4;
    int v[4];
    #pragma unroll
    for (int i = 0; i < 4; ++i) v[i] = (base + i < N) ? deg[base + i] : 0;
    int ts = v[0] + v[1] + v[2] + v[3];
    int incl = ts;
    #pragma unroll
    for (int d = 1; d < 64; d <<= 1) { int u = __shfl_up(incl, d); if (lane >= d) incl += u; }
    if (lane == 63) wtot[wid] = incl;
    __syncthreads();
    int wbase = 0;
    for (int w = 0; w < wid; ++w) wbase += wtot[w];
    int run = wbase + incl - ts;
    #pragma unroll
    for (int i = 0; i < 4; ++i) { if (base + i < N) offs[base + i] = run; run += v[i]; }
    if (tid == 255) bsum[blockIdx.x] = wbase + incl;
}

__global__ __launch_bounds__(256) void k_scan2(int* __restrict__ bsum, int NB) {
    __shared__ int wtot[4];
    int tid = threadIdx.x, lane = tid & 63, wid = tid >> 6;
    int v = (tid < NB) ? bsum[tid] : 0;
    int incl = v;
    #pragma unroll
    for (int d = 1; d < 64; d <<= 1) { int u = __shfl_up(incl, d); if (lane >= d) incl += u; }
    if (lane == 63) wtot[wid] = incl;
    __syncthreads();
    int wbase = 0;
    for (int w = 0; w < wid; ++w) wbase += wtot[w];
    if (tid < NB) bsum[tid] = wbase + incl - v;
}

__global__ __launch_bounds__(256) void k_scan3(
    int* __restrict__ offs, const int* __restrict__ bsum, int* __restrict__ cursor, int N) {
    int i = blockIdx.x * blockDim.x + threadIdx.x;
    if (i >= N) return;
    int v = offs[i] + bsum[i >> 10];
    offs[i] = v;
    cursor[i] = v;
}

__global__ __launch_bounds__(256) void k_scatter_offs(
    const int* __restrict__ ei, const int* __restrict__ rel,
    const float* __restrict__ eh, const float* __restrict__ et, const float* __restrict__ er,
    int* __restrict__ cursor, unsigned* __restrict__ csr, int E, int nE) {
    int e = blockIdx.x * blockDim.x + threadIdx.x;
    if (e >= E) return;
    int h = ei[e], t = ei[E + e], r = rel[e];
    float erv = er[r];
    float lh = eh[h] + erv; lh = lh > 0.f ? lh : 0.01f * lh;
    float lt = et[t] + erv; lt = lt > 0.f ? lt : 0.01f * lt;
    unsigned zh = (__float_as_uint(__expf(lh)) & 0xFFFFFC00u) | (unsigned)r;
    unsigned zt = (__float_as_uint(__expf(lt)) & 0xFFFFFC00u) | (unsigned)r;
    int ph = atomicAdd(&cursor[h], 1);
    csr[ph] = zh;
    int pt = atomicAdd(&cursor[nE + t], 1);
    csr[pt] = zt;
}

__global__ __launch_bounds__(256) void k_out_offs(
    const int* __restrict__ offs, const int* __restrict__ deg, const unsigned* __restrict__ csr,
    const __half* __restrict__ Mh, const __half* __restrict__ Mt, const float* __restrict__ br,
    float* __restrict__ out, int nE) {
    int wid = (blockIdx.x * blockDim.x + threadIdx.x) >> 6;
    int lane = threadIdx.x & 63;
    if (wid >= nE) return;
    int dH = deg[wid], dT = deg[nE + wid];
    size_t offH = (size_t)offs[wid], offT = (size_t)offs[nE + wid];
    float4 accH = {0, 0, 0, 0}, accT = {0, 0, 0, 0};
    float sH = 0.f, sT = 0.f;
    int dM = max(dH, dT);
    for (int b = 0; b < dM; b += 64) {
        int kH = min(64, dH - b);
        int kT = min(64, dT - b);
        unsigned eH = 0, eT = 0;
        if (lane < kH) eH = csr[offH + b + lane];
        if (lane < kT) eT = csr[offT + b + lane];
        int kk = max(kH, kT);
        for (int j = 0; j < kk; ++j) {
            unsigned cH = (unsigned)__shfl((int)eH, j);
            unsigned cT = (unsigned)__shfl((int)eT, j);
            if (j < kH) {
                float z = __uint_as_float(cH & 0xFFFFFC00u);
                int r = (int)(cH & 0x3FFu);
                const __half2* mp = (const __half2*)(Mh + ((size_t)r << 8) + (lane << 2));
                float2 m01 = __half22float2(mp[0]);
                float2 m23 = __half22float2(mp[1]);
                accH.x += z * m01.x; accH.y += z * m01.y;
                accH.z += z * m23.x; accH.w += z * m23.y;
                sH += z;
            }
            if (j < kT) {
                float z = __uint_as_float(cT & 0xFFFFFC00u);
                int r = (int)(cT & 0x3FFu);
                const __half2* mp = (const __half2*)(Mt + ((size_t)r << 8) + (lane << 2));
                float2 m01 = __half22float2(mp[0]);
                float2 m23 = __half22float2(mp[1]);
                accT.x += z * m01.x; accT.y += z * m01.y;
                accT.z += z * m23.x; accT.w += z * m23.y;
                sT += z;
            }
        }
    }
    float iH = 1.f / (sH + 1e-16f);
    float iT = 1.f / (sT + 1e-16f);
    float4 bv = *(const float4*)(br + lane * 4);
    float4 o;
    o.x = accH.x * iH + accT.x * iT + bv.x;
    o.y = accH.y * iH + accT.y * iT + bv.y;
    o.z = accH.z * iH + accT.z * iT + bv.z;
    o.w = accH.w * iH + accT.w * iT + bv.w;
    *(float4*)(out + (size_t)wid * 256 + lane * 4) = o;
}

extern "C" void kernel_launch(void* const* d_in, const int* in_sizes, int n_in,
                              void* d_out, int out_size, void* d_ws, size_t ws_size,
                              hipStream_t stream) {
    const float* xe  = (const float*)d_in[0];
    const float* xr  = (const float*)d_in[1];
    const int*   ei  = (const int*)d_in[2];
    const int*   rel = (const int*)d_in[3];
    const float* wah = (const float*)d_in[5];
    const float* wat = (const float*)d_in[6];
    const float* war = (const float*)d_in[7];
    const float* W1  = (const float*)d_in[8];
    const float* b1  = (const float*)d_in[9];
    const float* W2  = (const float*)d_in[10];
    const float* b2  = (const float*)d_in[11];
    const float* Wr  = (const float*)d_in[12];
    const float* br  = (const float*)d_in[13];
    float* out = (float*)d_out;

    const int nE = in_sizes[0] / 128;   // 100000
    const int nR = in_sizes[1] / 128;   // 1000
    const int E  = in_sizes[3];         // 1000000
    const int N  = 2 * nE;
    const int NBUCK = (N + VNB2 - 1) >> VSH2;   // 3125 buckets

    float* ws = (float*)d_ws;
    size_t o = 0;
    auto alloc = [&](size_t words) { size_t r = o; o += (words + 3) & ~(size_t)3; return r; };
    float* eh     = ws + alloc(nE);
    float* et     = ws + alloc(nE);
    float* er     = ws + alloc(nR);
    __half* Mh    = (__half*)(ws + alloc((size_t)nR * 128));   // nR*256 halves
    __half* Mt    = (__half*)(ws + alloc((size_t)nR * 128));
    int*   bcur   = (int*)(ws + alloc((size_t)NBUCK * SEG));
    size_t common_words = o;

    size_t coarse_words = ((size_t)NBUCK * SEG * SCAP + 1) / 2;   // uint16 -> words
    bool planNew = (ws_size >= (common_words + coarse_words + 64) * 4);

    k_scores<<<(nE + nR + 3) / 4, 256, 0, stream>>>(xe, xr, wah, wat, war, eh, et, er, nE, nR);
    k_rel<<<nR, 256, 0, stream>>>(xr, W1, b1, W2, b2, Wr, Mh, Mt);

    if (planNew) {
        unsigned short* coarse = (unsigned short*)(ws + alloc(coarse_words));
        hipMemsetAsync(bcur, 0, (size_t)NBUCK * SEG * sizeof(int), stream);
        k_bin2<<<(E + 255) / 256, 256, 0, stream>>>(ei, rel, bcur, coarse, E);
        k_group_out2<<<NBUCK, 256, 0, stream>>>(bcur, coarse, eh, et, er, Mh, Mt, br, out, nE);
    } else {
        int* cursor = (int*)(ws + alloc(N));
        int* deg    = (int*)(ws + alloc(N));
        int* offs   = (int*)(ws + alloc(N));
        int* bsum   = (int*)(ws + alloc(512));
        unsigned* csr = (unsigned*)(ws + alloc(2 * (size_t)E));
        const int NB = (N + 1023) / 1024;
        hipMemsetAsync(deg, 0, (size_t)N * sizeof(int), stream);
        k_hist<<<(E + 255) / 256, 256, 0, stream>>>(ei, deg, E, nE);
        k_scan1<<<NB, 256, 0, stream>>>(deg, offs, bsum, N);
        k_scan2<<<1, 256, 0, stream>>>(bsum, NB);
        k_scan3<<<(N + 255) / 256, 256, 0, stream>>>(offs, bsum, cursor, N);
        k_scatter_offs<<<(E + 255) / 256, 256, 0, stream>>>(ei, rel, eh, et, er, cursor, csr, E, nE);
        k_out_offs<<<(nE + 3) / 4, 256, 0, stream>>>(offs, deg, csr, Mh, Mt, br, out, nE);
    }
}

// Round 4
// 409.094 us; speedup vs baseline: 2.0044x; 1.0368x over previous
//
#include <hip/hip_runtime.h>
#include <hip/hip_fp16.h>

// R4: k_group_out2 was the top dispatch (117us) and is VALU-issue bound
// (VALUBusy 59.7%, HBM 15%, FETCH=coarse buffer exactly, WRITE=output
// exactly). Cut instructions:
//   (1) split H/T inner loops: no beyond-degree table loads (old combined
//       max(dH,dT) loop wasted ~35% of loads + dependent VALU).
//   (2) v_pk_fma_f32 via ext_vector float2 + __builtin_elementwise_fma:
//       8 scalar FMA -> 4 packed per entry-lane.
//   (3) flattened sort: fixed 1280-slot grid (8 seg x 160) as 5x256
//       coalesced passes, entries staged in registers (KPT=5, static
//       indexing) -- kills the 8 serialized 80/256-active sub-loops and
//       the ent[] LDS round trip.
//   (4) er[] staged in LDS once per block (2M random L2 gathers -> LDS).
// k_bin2 (segmented 25K-counter binning, single-XCD-writer lines) fixed the
// R1 atomic disaster and is now <117us -> untouched.
// NOTE: all scatter stores remain PLAIN stores (nontemporal broke coherence
// with harness poison-writes in a previous session).

#define VNB2  64                  // v-nodes per bucket (32 e-nodes)
#define VSH2  6
#define SEG   8                   // segments per bucket (~per-XCD)
#define SCAP  160                 // entries per segment (mean 80, +9 sigma)
#define KPT   5                   // SEG*SCAP = 1280 = KPT*256 slots
#define MAXD  64                  // per-node degree cap in output stage

typedef float v2f __attribute__((ext_vector_type(2)));

// K1: eh[n]=x_e[n]·w_ah, et[n]=x_e[n]·w_at; er[r]=x_r[r]·w_ar. One wave/row.
__global__ __launch_bounds__(256) void k_scores(
    const float* __restrict__ xe, const float* __restrict__ xr,
    const float* __restrict__ wah, const float* __restrict__ wat, const float* __restrict__ war,
    float* __restrict__ eh, float* __restrict__ et, float* __restrict__ er,
    int nE, int nR) {
    int wid = (blockIdx.x * blockDim.x + threadIdx.x) >> 6;
    int lane = threadIdx.x & 63;
    if (wid < nE) {
        float2 x2 = *(const float2*)(xe + (size_t)wid * 128 + lane * 2);
        float2 a2 = *(const float2*)(wah + lane * 2);
        float2 b2 = *(const float2*)(wat + lane * 2);
        float dh = x2.x * a2.x + x2.y * a2.y;
        float dt = x2.x * b2.x + x2.y * b2.y;
        #pragma unroll
        for (int m = 32; m >= 1; m >>= 1) { dh += __shfl_xor(dh, m); dt += __shfl_xor(dt, m); }
        if (lane == 0) { eh[wid] = dh; et[wid] = dt; }
    } else if (wid < nE + nR) {
        int r = wid - nE;
        float2 x2 = *(const float2*)(xr + (size_t)r * 128 + lane * 2);
        float2 c2 = *(const float2*)(war + lane * 2);
        float d = x2.x * c2.x + x2.y * c2.y;
        #pragma unroll
        for (int m = 32; m >= 1; m >>= 1) d += __shfl_xor(d, m);
        if (lane == 0) er[r] = d;
    }
}

// K2: fused relation pipeline (1 block/relation, 256 thr):
//   hidden = x_r@W1+b1 ; msg = x_r + hidden@W2+b2 ; Mh/Mt = msg@Wr halves (fp16)
__global__ __launch_bounds__(256) void k_rel(
    const float* __restrict__ xr,
    const float* __restrict__ W1, const float* __restrict__ b1,
    const float* __restrict__ W2, const float* __restrict__ b2,
    const float* __restrict__ Wr,
    __half* __restrict__ Mh, __half* __restrict__ Mt) {
    __shared__ float xs[128];
    __shared__ float hs[256];
    __shared__ float ms[128];
    int r = blockIdx.x, j = threadIdx.x;
    if (j < 128) xs[j] = xr[(size_t)r * 128 + j];
    __syncthreads();
    {
        float acc = b1[j];
        #pragma unroll 4
        for (int k = 0; k < 128; ++k) acc += xs[k] * W1[k * 256 + j];
        hs[j] = acc;
    }
    __syncthreads();
    if (j < 128) {
        float acc = b2[j] + xs[j];
        #pragma unroll 4
        for (int k = 0; k < 256; ++k) acc += hs[k] * W2[k * 128 + j];
        ms[j] = acc;
    }
    __syncthreads();
    {
        float ah = 0.f, at_ = 0.f;
        #pragma unroll 4
        for (int i = 0; i < 128; ++i) {
            float m = ms[i];
            ah  += m * Wr[i * 256 + j];
            at_ += m * Wr[(128 + i) * 256 + j];
        }
        Mh[(size_t)r * 256 + j] = __float2half(ah);
        Mt[(size_t)r * 256 + j] = __float2half(at_);
    }
}

// K3: segmented coarse binning. 25K counters (fan-in ~80/address); segment
// chosen by blockIdx&7 so each segment's lines have a single XCD writer.
__global__ __launch_bounds__(256) void k_bin2(
    const int* __restrict__ ei, const int* __restrict__ rel,
    int* __restrict__ bcur, unsigned short* __restrict__ coarse, int E) {
    int e = blockIdx.x * blockDim.x + threadIdx.x;
    if (e >= E) return;
    int s = blockIdx.x & (SEG - 1);
    unsigned h = (unsigned)ei[e], t = (unsigned)ei[E + e], r = (unsigned)rel[e];
    unsigned vh = h << 1;          // head side: v = 2h
    unsigned vt = (t << 1) | 1u;   // tail side: v = 2t+1
    unsigned bh = vh >> VSH2, bt = vt >> VSH2;
    unsigned short evh = (unsigned short)(((vh & (VNB2 - 1u)) << 10) | r);
    unsigned short evt = (unsigned short)(((vt & (VNB2 - 1u)) << 10) | r);
    int ph = atomicAdd(&bcur[bh * SEG + s], 1);
    if (ph < SCAP) coarse[((size_t)bh * SEG + s) * SCAP + ph] = evh;
    int pt = atomicAdd(&bcur[bt * SEG + s], 1);
    if (pt < SCAP) coarse[((size_t)bt * SEG + s) * SCAP + pt] = evt;
}

// K4: fused group + output, instruction-lean version.
__global__ __launch_bounds__(256) void k_group_out3(
    const int* __restrict__ bcur, const unsigned short* __restrict__ coarse,
    const float* __restrict__ eh, const float* __restrict__ et, const float* __restrict__ er,
    const __half* __restrict__ Mh, const __half* __restrict__ Mt,
    const float* __restrict__ br, float* __restrict__ out, int nE, int nR) {
    __shared__ unsigned short csr[SEG * SCAP];     // 2560 B
    __shared__ float er_s[1024];                   // 4 KB
    __shared__ int cnt[VNB2], offs[VNB2], cur[VNB2];
    __shared__ int segc[SEG];
    int b = blockIdx.x, tid = threadIdx.x;
    if (tid < VNB2) cnt[tid] = 0;
    if (tid < SEG) segc[tid] = min(bcur[b * SEG + tid], SCAP);
    for (int i = tid; i < nR; i += 256) er_s[i] = er[i];
    __syncthreads();
    // phase 1: flattened coalesced load of the 1280-slot grid into registers
    // + LDS histogram. slot k covers [tid + k*256]; seg = slot/SCAP.
    const unsigned short* src = coarse + (size_t)b * SEG * SCAP;
    unsigned short ev[KPT];
    bool val[KPT];
    #pragma unroll
    for (int k = 0; k < KPT; ++k) {
        int slot = tid + k * 256;
        int s = slot / SCAP;
        int i = slot - s * SCAP;
        val[k] = (i < segc[s]);
        ev[k] = val[k] ? src[slot] : (unsigned short)0;
    }
    #pragma unroll
    for (int k = 0; k < KPT; ++k)
        if (val[k]) atomicAdd(&cnt[ev[k] >> 10], 1);
    __syncthreads();
    // phase 2: wave 0 scans the 64 node bins
    if (tid < 64) {
        int v = cnt[tid];
        int incl = v;
        #pragma unroll
        for (int d = 1; d < 64; d <<= 1) { int u = __shfl_up(incl, d); if (tid >= d) incl += u; }
        offs[tid] = incl - v;
        cur[tid] = incl - v;
    }
    __syncthreads();
    // phase 3: counting-sort rels into per-node CSR from registers
    #pragma unroll
    for (int k = 0; k < KPT; ++k) {
        if (val[k]) {
            int p = atomicAdd(&cur[ev[k] >> 10], 1);
            csr[p] = (unsigned short)(ev[k] & 1023u);
        }
    }
    __syncthreads();          // after this, cur[v] = end offset of node v
    // phase 4: wave per e-node; split H/T loops; packed-f32 FMA accumulate.
    int lane = tid & 63, wid = tid >> 6;
    float4 bv = *(const float4*)(br + lane * 4);
    int nbase = b * (VNB2 / 2);
    for (int li = wid; li < VNB2 / 2; li += 4) {
        int n = nbase + li;
        if (n >= nE) break;
        int oH = offs[2 * li];
        int oT = offs[2 * li + 1];
        int dH = min(cur[2 * li] - oH, MAXD);
        int dT = min(cur[2 * li + 1] - oT, MAXD);
        float ehn = eh[n], etn = et[n];
        unsigned eHv = 0u, eTv = 0u;
        if (lane < dH) {
            int r = csr[oH + lane];
            float l = ehn + er_s[r]; l = l > 0.f ? l : 0.01f * l;
            eHv = (__float_as_uint(__expf(l)) & 0xFFFFFC00u) | (unsigned)r;
        }
        if (lane < dT) {
            int r = csr[oT + lane];
            float l = etn + er_s[r]; l = l > 0.f ? l : 0.01f * l;
            eTv = (__float_as_uint(__expf(l)) & 0xFFFFFC00u) | (unsigned)r;
        }
        v2f accH01 = {0.f, 0.f}, accH23 = {0.f, 0.f};
        v2f accT01 = {0.f, 0.f}, accT23 = {0.f, 0.f};
        float sH = 0.f, sT = 0.f;
        for (int j = 0; j < dH; j += 4) {       // dH<=64: j+3 <= 63, shfl in range
            unsigned c4[4]; uint2 m4[4];
            #pragma unroll
            for (int i = 0; i < 4; ++i) c4[i] = (unsigned)__shfl((int)eHv, j + i);
            #pragma unroll
            for (int i = 0; i < 4; ++i)
                m4[i] = *(const uint2*)(Mh + (((size_t)(c4[i] & 0x3FFu)) << 8) + (lane << 2));
            #pragma unroll
            for (int i = 0; i < 4; ++i) {
                float z = __uint_as_float(c4[i] & 0xFFFFFC00u);
                float2 h01 = __half22float2(*(const __half2*)&m4[i].x);
                float2 h23 = __half22float2(*(const __half2*)&m4[i].y);
                v2f zz = {z, z};
                accH01 = __builtin_elementwise_fma(zz, (v2f){h01.x, h01.y}, accH01);
                accH23 = __builtin_elementwise_fma(zz, (v2f){h23.x, h23.y}, accH23);
                sH += z;
            }
        }
        for (int j = 0; j < dT; j += 4) {
            unsigned c4[4]; uint2 m4[4];
            #pragma unroll
            for (int i = 0; i < 4; ++i) c4[i] = (unsigned)__shfl((int)eTv, j + i);
            #pragma unroll
            for (int i = 0; i < 4; ++i)
                m4[i] = *(const uint2*)(Mt + (((size_t)(c4[i] & 0x3FFu)) << 8) + (lane << 2));
            #pragma unroll
            for (int i = 0; i < 4; ++i) {
                float z = __uint_as_float(c4[i] & 0xFFFFFC00u);
                float2 t01 = __half22float2(*(const __half2*)&m4[i].x);
                float2 t23 = __half22float2(*(const __half2*)&m4[i].y);
                v2f zz = {z, z};
                accT01 = __builtin_elementwise_fma(zz, (v2f){t01.x, t01.y}, accT01);
                accT23 = __builtin_elementwise_fma(zz, (v2f){t23.x, t23.y}, accT23);
                sT += z;
            }
        }
        float iH = 1.f / (sH + 1e-16f);
        float iT = 1.f / (sT + 1e-16f);
        float4 o;
        o.x = accH01.x * iH + accT01.x * iT + bv.x;
        o.y = accH01.y * iH + accT01.y * iT + bv.y;
        o.z = accH23.x * iH + accT23.x * iT + bv.z;
        o.w = accH23.y * iH + accT23.y * iT + bv.w;
        *(float4*)(out + (size_t)n * 256 + lane * 4) = o;
    }
}

// ---- Plan A fallback (ws too small): hist + scan + offset CSR ----
__global__ __launch_bounds__(256) void k_hist(
    const int* __restrict__ ei, int* __restrict__ deg, int E, int nE) {
    int e = blockIdx.x * blockDim.x + threadIdx.x;
    if (e >= E) return;
    atomicAdd(&deg[ei[e]], 1);
    atomicAdd(&deg[nE + ei[E + e]], 1);
}

__global__ __launch_bounds__(256) void k_scan1(
    const int* __restrict__ deg, int* __restrict__ offs, int* __restrict__ bsum, int N) {
    __shared__ int wtot[4];
    int tid = threadIdx.x, lane = tid & 63, wid = tid >> 6;
    int base = blockIdx.x * 1024 + tid * 4;
    int v[4];
    #pragma unroll
    for (int i = 0; i < 4; ++i) v[i] = (base + i < N) ? deg[base + i] : 0;
    int ts = v[0] + v[1] + v[2] + v[3];
    int incl = ts;
    #pragma unroll
    for (int d = 1; d < 64; d <<= 1) { int u = __shfl_up(incl, d); if (lane >= d) incl += u; }
    if (lane == 63) wtot[wid] = incl;
    __syncthreads();
    int wbase = 0;
    for (int w = 0; w < wid; ++w) wbase += wtot[w];
    int run = wbase + incl - ts;
    #pragma unroll
    for (int i = 0; i < 4; ++i) { if (base + i < N) offs[base + i] = run; run += v[i]; }
    if (tid == 255) bsum[blockIdx.x] = wbase + incl;
}

__global__ __launch_bounds__(256) void k_scan2(int* __restrict__ bsum, int NB) {
    __shared__ int wtot[4];
    int tid = threadIdx.x, lane = tid & 63, wid = tid >> 6;
    int v = (tid < NB) ? bsum[tid] : 0;
    int incl = v;
    #pragma unroll
    for (int d = 1; d < 64; d <<= 1) { int u = __shfl_up(incl, d); if (lane >= d) incl += u; }
    if (lane == 63) wtot[wid] = incl;
    __syncthreads();
    int wbase = 0;
    for (int w = 0; w < wid; ++w) wbase += wtot[w];
    if (tid < NB) bsum[tid] = wbase + incl - v;
}

__global__ __launch_bounds__(256) void k_scan3(
    int* __restrict__ offs, const int* __restrict__ bsum, int* __restrict__ cursor, int N) {
    int i = blockIdx.x * blockDim.x + threadIdx.x;
    if (i >= N) return;
    int v = offs[i] + bsum[i >> 10];
    offs[i] = v;
    cursor[i] = v;
}

__global__ __launch_bounds__(256) void k_scatter_offs(
    const int* __restrict__ ei, const int* __restrict__ rel,
    const float* __restrict__ eh, const float* __restrict__ et, const float* __restrict__ er,
    int* __restrict__ cursor, unsigned* __restrict__ csr, int E, int nE) {
    int e = blockIdx.x * blockDim.x + threadIdx.x;
    if (e >= E) return;
    int h = ei[e], t = ei[E + e], r = rel[e];
    float erv = er[r];
    float lh = eh[h] + erv; lh = lh > 0.f ? lh : 0.01f * lh;
    float lt = et[t] + erv; lt = lt > 0.f ? lt : 0.01f * lt;
    unsigned zh = (__float_as_uint(__expf(lh)) & 0xFFFFFC00u) | (unsigned)r;
    unsigned zt = (__float_as_uint(__expf(lt)) & 0xFFFFFC00u) | (unsigned)r;
    int ph = atomicAdd(&cursor[h], 1);
    csr[ph] = zh;
    int pt = atomicAdd(&cursor[nE + t], 1);
    csr[pt] = zt;
}

__global__ __launch_bounds__(256) void k_out_offs(
    const int* __restrict__ offs, const int* __restrict__ deg, const unsigned* __restrict__ csr,
    const __half* __restrict__ Mh, const __half* __restrict__ Mt, const float* __restrict__ br,
    float* __restrict__ out, int nE) {
    int wid = (blockIdx.x * blockDim.x + threadIdx.x) >> 6;
    int lane = threadIdx.x & 63;
    if (wid >= nE) return;
    int dH = deg[wid], dT = deg[nE + wid];
    size_t offH = (size_t)offs[wid], offT = (size_t)offs[nE + wid];
    float4 accH = {0, 0, 0, 0}, accT = {0, 0, 0, 0};
    float sH = 0.f, sT = 0.f;
    int dM = max(dH, dT);
    for (int b = 0; b < dM; b += 64) {
        int kH = min(64, dH - b);
        int kT = min(64, dT - b);
        unsigned eH = 0, eT = 0;
        if (lane < kH) eH = csr[offH + b + lane];
        if (lane < kT) eT = csr[offT + b + lane];
        int kk = max(kH, kT);
        for (int j = 0; j < kk; ++j) {
            unsigned cH = (unsigned)__shfl((int)eH, j);
            unsigned cT = (unsigned)__shfl((int)eT, j);
            if (j < kH) {
                float z = __uint_as_float(cH & 0xFFFFFC00u);
                int r = (int)(cH & 0x3FFu);
                const __half2* mp = (const __half2*)(Mh + ((size_t)r << 8) + (lane << 2));
                float2 m01 = __half22float2(mp[0]);
                float2 m23 = __half22float2(mp[1]);
                accH.x += z * m01.x; accH.y += z * m01.y;
                accH.z += z * m23.x; accH.w += z * m23.y;
                sH += z;
            }
            if (j < kT) {
                float z = __uint_as_float(cT & 0xFFFFFC00u);
                int r = (int)(cT & 0x3FFu);
                const __half2* mp = (const __half2*)(Mt + ((size_t)r << 8) + (lane << 2));
                float2 m01 = __half22float2(mp[0]);
                float2 m23 = __half22float2(mp[1]);
                accT.x += z * m01.x; accT.y += z * m01.y;
                accT.z += z * m23.x; accT.w += z * m23.y;
                sT += z;
            }
        }
    }
    float iH = 1.f / (sH + 1e-16f);
    float iT = 1.f / (sT + 1e-16f);
    float4 bv = *(const float4*)(br + lane * 4);
    float4 o;
    o.x = accH.x * iH + accT.x * iT + bv.x;
    o.y = accH.y * iH + accT.y * iT + bv.y;
    o.z = accH.z * iH + accT.z * iT + bv.z;
    o.w = accH.w * iH + accT.w * iT + bv.w;
    *(float4*)(out + (size_t)wid * 256 + lane * 4) = o;
}

extern "C" void kernel_launch(void* const* d_in, const int* in_sizes, int n_in,
                              void* d_out, int out_size, void* d_ws, size_t ws_size,
                              hipStream_t stream) {
    const float* xe  = (const float*)d_in[0];
    const float* xr  = (const float*)d_in[1];
    const int*   ei  = (const int*)d_in[2];
    const int*   rel = (const int*)d_in[3];
    const float* wah = (const float*)d_in[5];
    const float* wat = (const float*)d_in[6];
    const float* war = (const float*)d_in[7];
    const float* W1  = (const float*)d_in[8];
    const float* b1  = (const float*)d_in[9];
    const float* W2  = (const float*)d_in[10];
    const float* b2  = (const float*)d_in[11];
    const float* Wr  = (const float*)d_in[12];
    const float* br  = (const float*)d_in[13];
    float* out = (float*)d_out;

    const int nE = in_sizes[0] / 128;   // 100000
    const int nR = in_sizes[1] / 128;   // 1000
    const int E  = in_sizes[3];         // 1000000
    const int N  = 2 * nE;
    const int NBUCK = (N + VNB2 - 1) >> VSH2;   // 3125 buckets

    float* ws = (float*)d_ws;
    size_t o = 0;
    auto alloc = [&](size_t words) { size_t r = o; o += (words + 3) & ~(size_t)3; return r; };
    float* eh     = ws + alloc(nE);
    float* et     = ws + alloc(nE);
    float* er     = ws + alloc(nR);
    __half* Mh    = (__half*)(ws + alloc((size_t)nR * 128));   // nR*256 halves
    __half* Mt    = (__half*)(ws + alloc((size_t)nR * 128));
    int*   bcur   = (int*)(ws + alloc((size_t)NBUCK * SEG));
    size_t common_words = o;

    size_t coarse_words = ((size_t)NBUCK * SEG * SCAP + 1) / 2;   // uint16 -> words
    bool planNew = (ws_size >= (common_words + coarse_words + 64) * 4);

    k_scores<<<(nE + nR + 3) / 4, 256, 0, stream>>>(xe, xr, wah, wat, war, eh, et, er, nE, nR);
    k_rel<<<nR, 256, 0, stream>>>(xr, W1, b1, W2, b2, Wr, Mh, Mt);

    if (planNew) {
        unsigned short* coarse = (unsigned short*)(ws + alloc(coarse_words));
        hipMemsetAsync(bcur, 0, (size_t)NBUCK * SEG * sizeof(int), stream);
        k_bin2<<<(E + 255) / 256, 256, 0, stream>>>(ei, rel, bcur, coarse, E);
        k_group_out3<<<NBUCK, 256, 0, stream>>>(bcur, coarse, eh, et, er, Mh, Mt, br, out, nE, nR);
    } else {
        int* cursor = (int*)(ws + alloc(N));
        int* deg    = (int*)(ws + alloc(N));
        int* offs   = (int*)(ws + alloc(N));
        int* bsum   = (int*)(ws + alloc(512));
        unsigned* csr = (unsigned*)(ws + alloc(2 * (size_t)E));
        const int NB = (N + 1023) / 1024;
        hipMemsetAsync(deg, 0, (size_t)N * sizeof(int), stream);
        k_hist<<<(E + 255) / 256, 256, 0, stream>>>(ei, deg, E, nE);
        k_scan1<<<NB, 256, 0, stream>>>(deg, offs, bsum, N);
        k_scan2<<<1, 256, 0, stream>>>(bsum, NB);
        k_scan3<<<(N + 255) / 256, 256, 0, stream>>>(offs, bsum, cursor, N);
        k_scatter_offs<<<(E + 255) / 256, 256, 0, stream>>>(ei, rel, eh, et, er, cursor, csr, E, nE);
        k_out_offs<<<(nE + 3) / 4, 256, 0, stream>>>(offs, deg, csr, Mh, Mt, br, out, nE);
    }
}

// Round 5
// 337.788 us; speedup vs baseline: 2.4275x; 1.2111x over previous
//
#include <hip/hip_runtime.h>
#include <hip/hip_fp16.h>

// R5: kill k_bin2 (103us). R0 vs R4 comparison showed the scatter cost is
// NOT bytes (write 122MB vs 69MB, same ~110us) but uncoalesced VMEM
// transactions: 2M atomic-with-return + 2M dependent scattered stores
// ~= 4M transactions @ ~20G/s. Fix: deterministic two-level LDS counting
// sort where every global store is a coalesced run and atomics ~vanish.
//   k_hist1: per-block LDS histogram into 49 super-bins (v>>12). no atomics.
//   k_scanp: per-bin scan over block counts -> deterministic bases + totals.
//   k_part1: re-read edges, LDS-sort chunk by super-bin, write runs (~336B)
//            at precomputed bases. zero global atomics, coalesced stores.
//   k_part2: read super-bin chunks, LDS-sort into 64 buckets (64 v each),
//            write u16 entries in ~128B runs; 1 atomic per (bucket,chunk),
//            fan-in 11.
//   k_group_out4: proven group+output structure; 8-seg merge replaced by a
//            flat <=1024-entry load. entry u16 = (v&63)<<10 | rel; z is
//            recomputed at f32 (z depends only on (node, rel)).
// NOTE: all stores PLAIN (nontemporal broke coherence with harness poison).

#define CH1    2048               // edges per hist/part1 block
#define SUPW   4096               // v-nodes per super-bin
#define CAP1   45056              // items per super-bin (mean 40960, +20sig)
#define CH2    4096               // items per part2 block
#define CHUNK2 (CAP1 / CH2)       // 11
#define CAP2   1024               // entries per bucket (mean 640, +15sig)
#define MAXD   64                 // per-node degree cap in output stage

typedef float v2f __attribute__((ext_vector_type(2)));

// K1: eh[n]=x_e[n]·w_ah, et[n]=x_e[n]·w_at; er[r]=x_r[r]·w_ar. One wave/row.
__global__ __launch_bounds__(256) void k_scores(
    const float* __restrict__ xe, const float* __restrict__ xr,
    const float* __restrict__ wah, const float* __restrict__ wat, const float* __restrict__ war,
    float* __restrict__ eh, float* __restrict__ et, float* __restrict__ er,
    int nE, int nR) {
    int wid = (blockIdx.x * blockDim.x + threadIdx.x) >> 6;
    int lane = threadIdx.x & 63;
    if (wid < nE) {
        float2 x2 = *(const float2*)(xe + (size_t)wid * 128 + lane * 2);
        float2 a2 = *(const float2*)(wah + lane * 2);
        float2 b2 = *(const float2*)(wat + lane * 2);
        float dh = x2.x * a2.x + x2.y * a2.y;
        float dt = x2.x * b2.x + x2.y * b2.y;
        #pragma unroll
        for (int m = 32; m >= 1; m >>= 1) { dh += __shfl_xor(dh, m); dt += __shfl_xor(dt, m); }
        if (lane == 0) { eh[wid] = dh; et[wid] = dt; }
    } else if (wid < nE + nR) {
        int r = wid - nE;
        float2 x2 = *(const float2*)(xr + (size_t)r * 128 + lane * 2);
        float2 c2 = *(const float2*)(war + lane * 2);
        float d = x2.x * c2.x + x2.y * c2.y;
        #pragma unroll
        for (int m = 32; m >= 1; m >>= 1) d += __shfl_xor(d, m);
        if (lane == 0) er[r] = d;
    }
}

// K2: fused relation pipeline (1 block/relation, 256 thr):
//   hidden = x_r@W1+b1 ; msg = x_r + hidden@W2+b2 ; Mh/Mt = msg@Wr halves (fp16)
__global__ __launch_bounds__(256) void k_rel(
    const float* __restrict__ xr,
    const float* __restrict__ W1, const float* __restrict__ b1,
    const float* __restrict__ W2, const float* __restrict__ b2,
    const float* __restrict__ Wr,
    __half* __restrict__ Mh, __half* __restrict__ Mt) {
    __shared__ float xs[128];
    __shared__ float hs[256];
    __shared__ float ms[128];
    int r = blockIdx.x, j = threadIdx.x;
    if (j < 128) xs[j] = xr[(size_t)r * 128 + j];
    __syncthreads();
    {
        float acc = b1[j];
        #pragma unroll 4
        for (int k = 0; k < 128; ++k) acc += xs[k] * W1[k * 256 + j];
        hs[j] = acc;
    }
    __syncthreads();
    if (j < 128) {
        float acc = b2[j] + xs[j];
        #pragma unroll 4
        for (int k = 0; k < 256; ++k) acc += hs[k] * W2[k * 128 + j];
        ms[j] = acc;
    }
    __syncthreads();
    {
        float ah = 0.f, at_ = 0.f;
        #pragma unroll 4
        for (int i = 0; i < 128; ++i) {
            float m = ms[i];
            ah  += m * Wr[i * 256 + j];
            at_ += m * Wr[(128 + i) * 256 + j];
        }
        Mh[(size_t)r * 256 + j] = __float2half(ah);
        Mt[(size_t)r * 256 + j] = __float2half(at_);
    }
}

// K3a: per-block histogram into 64 super-bins (49 used). Coalesced; no
// global atomics. hist layout bin-major [64][512] for the scan.
__global__ __launch_bounds__(256) void k_hist1(
    const int* __restrict__ ei, int* __restrict__ hist, int E) {
    __shared__ int cnt[64];
    int tid = threadIdx.x;
    if (tid < 64) cnt[tid] = 0;
    __syncthreads();
    int base = blockIdx.x * CH1;
    #pragma unroll
    for (int k = 0; k < CH1 / 256; ++k) {
        int e = base + k * 256 + tid;
        if (e < E) {
            unsigned vh = ((unsigned)ei[e]) << 1;
            unsigned vt = (((unsigned)ei[E + e]) << 1) | 1u;
            atomicAdd(&cnt[vh >> 12], 1);
            atomicAdd(&cnt[vt >> 12], 1);
        }
    }
    __syncthreads();
    if (tid < 64) hist[tid * 512 + blockIdx.x] = cnt[tid];
}

// K3b: per-bin exclusive scan over nblk block counts (512 slots, 2/thread).
// Writes back exclusive prefixes; totals to bcur1.
__global__ __launch_bounds__(256) void k_scanp(
    int* __restrict__ hist, int* __restrict__ bcur1, int nblk) {
    __shared__ int wtot[4];
    int bin = blockIdx.x, tid = threadIdx.x, lane = tid & 63, wid = tid >> 6;
    int j0 = 2 * tid, j1 = 2 * tid + 1;
    int v0 = (j0 < nblk) ? hist[bin * 512 + j0] : 0;
    int v1 = (j1 < nblk) ? hist[bin * 512 + j1] : 0;
    int ts = v0 + v1;
    int incl = ts;
    #pragma unroll
    for (int d = 1; d < 64; d <<= 1) { int u = __shfl_up(incl, d); if (lane >= d) incl += u; }
    if (lane == 63) wtot[wid] = incl;
    __syncthreads();
    int wbase = 0;
    for (int w = 0; w < wid; ++w) wbase += wtot[w];
    int excl = wbase + incl - ts;
    hist[bin * 512 + j0] = excl;
    hist[bin * 512 + j1] = excl + v0;
    if (tid == 255) bcur1[bin] = wbase + incl;
}

// K3c: LDS counting-sort of each 2048-edge chunk (4096 items) by super-bin;
// coalesced run writes at deterministic bases. item22 = (v&4095)<<10 | rel.
__global__ __launch_bounds__(256) void k_part1(
    const int* __restrict__ ei, const int* __restrict__ rel,
    const int* __restrict__ hist, unsigned* __restrict__ part1, int E) {
    __shared__ unsigned stage[CH1 * 2];            // 16 KB
    __shared__ int cnt[64], offs_[64], cur[64], gb[64];
    int tid = threadIdx.x;
    if (tid < 64) cnt[tid] = 0;
    __syncthreads();
    int base = blockIdx.x * CH1;
    unsigned wh[CH1 / 256], wt[CH1 / 256];
    bool ve[CH1 / 256];
    #pragma unroll
    for (int k = 0; k < CH1 / 256; ++k) {
        int e = base + k * 256 + tid;
        ve[k] = (e < E);
        unsigned h = 0, t = 0, r = 0;
        if (ve[k]) { h = (unsigned)ei[e]; t = (unsigned)ei[E + e]; r = (unsigned)rel[e]; }
        unsigned vh = h << 1, vt = (t << 1) | 1u;
        wh[k] = ((vh >> 12) << 26) | ((vh & 4095u) << 10) | r;
        wt[k] = ((vt >> 12) << 26) | ((vt & 4095u) << 10) | r;
        if (ve[k]) { atomicAdd(&cnt[wh[k] >> 26], 1); atomicAdd(&cnt[wt[k] >> 26], 1); }
    }
    __syncthreads();
    if (tid < 64) {                                 // wave 0 scans 64 bins
        int v = cnt[tid], incl = v;
        #pragma unroll
        for (int d = 1; d < 64; d <<= 1) { int u = __shfl_up(incl, d); if (tid >= d) incl += u; }
        offs_[tid] = incl - v;
        cur[tid] = incl - v;
        gb[tid] = hist[tid * 512 + blockIdx.x];
    }
    __syncthreads();
    #pragma unroll
    for (int k = 0; k < CH1 / 256; ++k) {
        if (ve[k]) {
            int p = atomicAdd(&cur[wh[k] >> 26], 1); stage[p] = wh[k];
            int q = atomicAdd(&cur[wt[k] >> 26], 1); stage[q] = wt[k];
        }
    }
    __syncthreads();
    int total = offs_[63] + cnt[63];
    for (int p = tid; p < total; p += 256) {
        unsigned w = stage[p];
        int bin = w >> 26;
        int dst = gb[bin] + (p - offs_[bin]);
        if (dst < CAP1) part1[(size_t)bin * CAP1 + dst] = w & 0x03FFFFFFu;
    }
}

// K3d: sort super-bin chunks into 64 buckets of 64 v-nodes. entry u16 =
// (v&63)<<10 | rel. 1 global atomic per (bucket, chunk): fan-in CHUNK2=11.
__global__ __launch_bounds__(256) void k_part2(
    const int* __restrict__ bcur1, const unsigned* __restrict__ part1,
    int* __restrict__ bcur2, unsigned short* __restrict__ part2) {
    int s = blockIdx.x / CHUNK2, c = blockIdx.x % CHUNK2;
    int cnt_s = min(bcur1[s], CAP1);
    int start = c * CH2;
    if (start >= cnt_s) return;                     // uniform per block
    __shared__ unsigned stage[CH2];                 // 16 KB
    __shared__ int cnt[64], offs_[64], cur[64], gb[64];
    int tid = threadIdx.x;
    if (tid < 64) cnt[tid] = 0;
    __syncthreads();
    unsigned w_[CH2 / 256];
    bool v_[CH2 / 256];
    #pragma unroll
    for (int k = 0; k < CH2 / 256; ++k) {
        int i = start + k * 256 + tid;
        v_[k] = (i < cnt_s);
        unsigned it = v_[k] ? part1[(size_t)s * CAP1 + i] : 0u;
        unsigned sb = (it >> 16) & 63u;             // (v&4095)>>6
        unsigned entry = (((it >> 10) & 63u) << 10) | (it & 1023u);
        w_[k] = (sb << 16) | entry;
        if (v_[k]) atomicAdd(&cnt[sb], 1);
    }
    __syncthreads();
    if (tid < 64) {
        int v = cnt[tid], incl = v;
        #pragma unroll
        for (int d = 1; d < 64; d <<= 1) { int u = __shfl_up(incl, d); if (tid >= d) incl += u; }
        offs_[tid] = incl - v;
        cur[tid] = incl - v;
        gb[tid] = atomicAdd(&bcur2[s * 64 + tid], v);
    }
    __syncthreads();
    #pragma unroll
    for (int k = 0; k < CH2 / 256; ++k)
        if (v_[k]) { int p = atomicAdd(&cur[w_[k] >> 16], 1); stage[p] = w_[k]; }
    __syncthreads();
    int total = offs_[63] + cnt[63];
    for (int p = tid; p < total; p += 256) {
        unsigned w = stage[p];
        int sb = w >> 16;
        int dst = gb[sb] + (p - offs_[sb]);
        if (dst < CAP2) part2[((size_t)s * 64 + sb) * CAP2 + dst] = (unsigned short)w;
    }
}

// K4: fused group + output (proven structure; flat load, no segment merge).
__global__ __launch_bounds__(256) void k_group_out4(
    const int* __restrict__ bcur2, const unsigned short* __restrict__ part2,
    const float* __restrict__ eh, const float* __restrict__ et, const float* __restrict__ er,
    const __half* __restrict__ Mh, const __half* __restrict__ Mt,
    const float* __restrict__ br, float* __restrict__ out, int nE, int nR) {
    __shared__ unsigned short csr[CAP2];            // 2 KB
    __shared__ float er_s[1024];                    // 4 KB
    __shared__ int cnt[64], offs_[64], cur[64];
    int b = blockIdx.x, tid = threadIdx.x;
    int count = min(bcur2[b], CAP2);
    if (tid < 64) cnt[tid] = 0;
    for (int i = tid; i < nR; i += 256) er_s[i] = er[i];
    __syncthreads();
    unsigned short ev[CAP2 / 256];
    bool val[CAP2 / 256];
    #pragma unroll
    for (int k = 0; k < CAP2 / 256; ++k) {
        int i = tid + k * 256;
        val[k] = (i < count);
        ev[k] = val[k] ? part2[(size_t)b * CAP2 + i] : (unsigned short)0;
        if (val[k]) atomicAdd(&cnt[ev[k] >> 10], 1);
    }
    __syncthreads();
    if (tid < 64) {
        int v = cnt[tid], incl = v;
        #pragma unroll
        for (int d = 1; d < 64; d <<= 1) { int u = __shfl_up(incl, d); if (tid >= d) incl += u; }
        offs_[tid] = incl - v;
        cur[tid] = incl - v;
    }
    __syncthreads();
    #pragma unroll
    for (int k = 0; k < CAP2 / 256; ++k) {
        if (val[k]) {
            int p = atomicAdd(&cur[ev[k] >> 10], 1);
            csr[p] = (unsigned short)(ev[k] & 1023u);
        }
    }
    __syncthreads();          // cur[v] = end offset of node-local v
    int lane = tid & 63, wid = tid >> 6;
    float4 bv = *(const float4*)(br + lane * 4);
    int nbase = b * 32;
    for (int li = wid; li < 32; li += 4) {
        int n = nbase + li;
        if (n >= nE) break;
        int oH = offs_[2 * li];
        int oT = offs_[2 * li + 1];
        int dH = min(cur[2 * li] - oH, MAXD);
        int dT = min(cur[2 * li + 1] - oT, MAXD);
        float ehn = eh[n], etn = et[n];
        unsigned eHv = 0u, eTv = 0u;
        if (lane < dH) {
            int r = csr[oH + lane];
            float l = ehn + er_s[r]; l = l > 0.f ? l : 0.01f * l;
            eHv = (__float_as_uint(__expf(l)) & 0xFFFFFC00u) | (unsigned)r;
        }
        if (lane < dT) {
            int r = csr[oT + lane];
            float l = etn + er_s[r]; l = l > 0.f ? l : 0.01f * l;
            eTv = (__float_as_uint(__expf(l)) & 0xFFFFFC00u) | (unsigned)r;
        }
        v2f accH01 = {0.f, 0.f}, accH23 = {0.f, 0.f};
        v2f accT01 = {0.f, 0.f}, accT23 = {0.f, 0.f};
        float sH = 0.f, sT = 0.f;
        for (int j = 0; j < dH; j += 4) {        // dH<=64: j+3 <= 63, shfl ok
            unsigned c4[4]; uint2 m4[4];
            #pragma unroll
            for (int i = 0; i < 4; ++i) c4[i] = (unsigned)__shfl((int)eHv, j + i);
            #pragma unroll
            for (int i = 0; i < 4; ++i)
                m4[i] = *(const uint2*)(Mh + (((size_t)(c4[i] & 0x3FFu)) << 8) + (lane << 2));
            #pragma unroll
            for (int i = 0; i < 4; ++i) {
                float z = __uint_as_float(c4[i] & 0xFFFFFC00u);
                float2 h01 = __half22float2(*(const __half2*)&m4[i].x);
                float2 h23 = __half22float2(*(const __half2*)&m4[i].y);
                v2f zz = {z, z};
                accH01 = __builtin_elementwise_fma(zz, (v2f){h01.x, h01.y}, accH01);
                accH23 = __builtin_elementwise_fma(zz, (v2f){h23.x, h23.y}, accH23);
                sH += z;
            }
        }
        for (int j = 0; j < dT; j += 4) {
            unsigned c4[4]; uint2 m4[4];
            #pragma unroll
            for (int i = 0; i < 4; ++i) c4[i] = (unsigned)__shfl((int)eTv, j + i);
            #pragma unroll
            for (int i = 0; i < 4; ++i)
                m4[i] = *(const uint2*)(Mt + (((size_t)(c4[i] & 0x3FFu)) << 8) + (lane << 2));
            #pragma unroll
            for (int i = 0; i < 4; ++i) {
                float z = __uint_as_float(c4[i] & 0xFFFFFC00u);
                float2 t01 = __half22float2(*(const __half2*)&m4[i].x);
                float2 t23 = __half22float2(*(const __half2*)&m4[i].y);
                v2f zz = {z, z};
                accT01 = __builtin_elementwise_fma(zz, (v2f){t01.x, t01.y}, accT01);
                accT23 = __builtin_elementwise_fma(zz, (v2f){t23.x, t23.y}, accT23);
                sT += z;
            }
        }
        float iH = 1.f / (sH + 1e-16f);
        float iT = 1.f / (sT + 1e-16f);
        float4 o;
        o.x = accH01.x * iH + accT01.x * iT + bv.x;
        o.y = accH01.y * iH + accT01.y * iT + bv.y;
        o.z = accH23.x * iH + accT23.x * iT + bv.z;
        o.w = accH23.y * iH + accT23.y * iT + bv.w;
        *(float4*)(out + (size_t)n * 256 + lane * 4) = o;
    }
}

// ---- Plan A fallback (ws too small): hist + scan + offset CSR ----
__global__ __launch_bounds__(256) void k_hist(
    const int* __restrict__ ei, int* __restrict__ deg, int E, int nE) {
    int e = blockIdx.x * blockDim.x + threadIdx.x;
    if (e >= E) return;
    atomicAdd(&deg[ei[e]], 1);
    atomicAdd(&deg[nE + ei[E + e]], 1);
}

__global__ __launch_bounds__(256) void k_scan1(
    const int* __restrict__ deg, int* __restrict__ offs, int* __restrict__ bsum, int N) {
    __shared__ int wtot[4];
    int tid = threadIdx.x, lane = tid & 63, wid = tid >> 6;
    int base = blockIdx.x * 1024 + tid * 4;
    int v[4];
    #pragma unroll
    for (int i = 0; i < 4; ++i) v[i] = (base + i < N) ? deg[base + i] : 0;
    int ts = v[0] + v[1] + v[2] + v[3];
    int incl = ts;
    #pragma unroll
    for (int d = 1; d < 64; d <<= 1) { int u = __shfl_up(incl, d); if (lane >= d) incl += u; }
    if (lane == 63) wtot[wid] = incl;
    __syncthreads();
    int wbase = 0;
    for (int w = 0; w < wid; ++w) wbase += wtot[w];
    int run = wbase + incl - ts;
    #pragma unroll
    for (int i = 0; i < 4; ++i) { if (base + i < N) offs[base + i] = run; run += v[i]; }
    if (tid == 255) bsum[blockIdx.x] = wbase + incl;
}

__global__ __launch_bounds__(256) void k_scan2(int* __restrict__ bsum, int NB) {
    __shared__ int wtot[4];
    int tid = threadIdx.x, lane = tid & 63, wid = tid >> 6;
    int v = (tid < NB) ? bsum[tid] : 0;
    int incl = v;
    #pragma unroll
    for (int d = 1; d < 64; d <<= 1) { int u = __shfl_up(incl, d); if (lane >= d) incl += u; }
    if (lane == 63) wtot[wid] = incl;
    __syncthreads();
    int wbase = 0;
    for (int w = 0; w < wid; ++w) wbase += wtot[w];
    if (tid < NB) bsum[tid] = wbase + incl - v;
}

__global__ __launch_bounds__(256) void k_scan3(
    int* __restrict__ offs, const int* __restrict__ bsum, int* __restrict__ cursor, int N) {
    int i = blockIdx.x * blockDim.x + threadIdx.x;
    if (i >= N) return;
    int v = offs[i] + bsum[i >> 10];
    offs[i] = v;
    cursor[i] = v;
}

__global__ __launch_bounds__(256) void k_scatter_offs(
    const int* __restrict__ ei, const int* __restrict__ rel,
    const float* __restrict__ eh, const float* __restrict__ et, const float* __restrict__ er,
    int* __restrict__ cursor, unsigned* __restrict__ csr, int E, int nE) {
    int e = blockIdx.x * blockDim.x + threadIdx.x;
    if (e >= E) return;
    int h = ei[e], t = ei[E + e], r = rel[e];
    float erv = er[r];
    float lh = eh[h] + erv; lh = lh > 0.f ? lh : 0.01f * lh;
    float lt = et[t] + erv; lt = lt > 0.f ? lt : 0.01f * lt;
    unsigned zh = (__float_as_uint(__expf(lh)) & 0xFFFFFC00u) | (unsigned)r;
    unsigned zt = (__float_as_uint(__expf(lt)) & 0xFFFFFC00u) | (unsigned)r;
    int ph = atomicAdd(&cursor[h], 1);
    csr[ph] = zh;
    int pt = atomicAdd(&cursor[nE + t], 1);
    csr[pt] = zt;
}

__global__ __launch_bounds__(256) void k_out_offs(
    const int* __restrict__ offs, const int* __restrict__ deg, const unsigned* __restrict__ csr,
    const __half* __restrict__ Mh, const __half* __restrict__ Mt, const float* __restrict__ br,
    float* __restrict__ out, int nE) {
    int wid = (blockIdx.x * blockDim.x + threadIdx.x) >> 6;
    int lane = threadIdx.x & 63;
    if (wid >= nE) return;
    int dH = deg[wid], dT = deg[nE + wid];
    size_t offH = (size_t)offs[wid], offT = (size_t)offs[nE + wid];
    float4 accH = {0, 0, 0, 0}, accT = {0, 0, 0, 0};
    float sH = 0.f, sT = 0.f;
    int dM = max(dH, dT);
    for (int b = 0; b < dM; b += 64) {
        int kH = min(64, dH - b);
        int kT = min(64, dT - b);
        unsigned eH = 0, eT = 0;
        if (lane < kH) eH = csr[offH + b + lane];
        if (lane < kT) eT = csr[offT + b + lane];
        int kk = max(kH, kT);
        for (int j = 0; j < kk; ++j) {
            unsigned cH = (unsigned)__shfl((int)eH, j);
            unsigned cT = (unsigned)__shfl((int)eT, j);
            if (j < kH) {
                float z = __uint_as_float(cH & 0xFFFFFC00u);
                int r = (int)(cH & 0x3FFu);
                const __half2* mp = (const __half2*)(Mh + ((size_t)r << 8) + (lane << 2));
                float2 m01 = __half22float2(mp[0]);
                float2 m23 = __half22float2(mp[1]);
                accH.x += z * m01.x; accH.y += z * m01.y;
                accH.z += z * m23.x; accH.w += z * m23.y;
                sH += z;
            }
            if (j < kT) {
                float z = __uint_as_float(cT & 0xFFFFFC00u);
                int r = (int)(cT & 0x3FFu);
                const __half2* mp = (const __half2*)(Mt + ((size_t)r << 8) + (lane << 2));
                float2 m01 = __half22float2(mp[0]);
                float2 m23 = __half22float2(mp[1]);
                accT.x += z * m01.x; accT.y += z * m01.y;
                accT.z += z * m23.x; accT.w += z * m23.y;
                sT += z;
            }
        }
    }
    float iH = 1.f / (sH + 1e-16f);
    float iT = 1.f / (sT + 1e-16f);
    float4 bv = *(const float4*)(br + lane * 4);
    float4 o;
    o.x = accH.x * iH + accT.x * iT + bv.x;
    o.y = accH.y * iH + accT.y * iT + bv.y;
    o.z = accH.z * iH + accT.z * iT + bv.z;
    o.w = accH.w * iH + accT.w * iT + bv.w;
    *(float4*)(out + (size_t)wid * 256 + lane * 4) = o;
}

extern "C" void kernel_launch(void* const* d_in, const int* in_sizes, int n_in,
                              void* d_out, int out_size, void* d_ws, size_t ws_size,
                              hipStream_t stream) {
    const float* xe  = (const float*)d_in[0];
    const float* xr  = (const float*)d_in[1];
    const int*   ei  = (const int*)d_in[2];
    const int*   rel = (const int*)d_in[3];
    const float* wah = (const float*)d_in[5];
    const float* wat = (const float*)d_in[6];
    const float* war = (const float*)d_in[7];
    const float* W1  = (const float*)d_in[8];
    const float* b1  = (const float*)d_in[9];
    const float* W2  = (const float*)d_in[10];
    const float* b2  = (const float*)d_in[11];
    const float* Wr  = (const float*)d_in[12];
    const float* br  = (const float*)d_in[13];
    float* out = (float*)d_out;

    const int nE = in_sizes[0] / 128;   // 100000
    const int nR = in_sizes[1] / 128;   // 1000
    const int E  = in_sizes[3];         // 1000000
    const int N  = 2 * nE;              // 200000 v-nodes
    const int NSUP  = (N + SUPW - 1) / SUPW;    // 49
    const int NBUCK = NSUP * 64;                // 3136
    const int NBLK1 = (E + CH1 - 1) / CH1;      // 489

    float* ws = (float*)d_ws;
    size_t o = 0;
    auto alloc = [&](size_t words) { size_t r = o; o += (words + 3) & ~(size_t)3; return r; };
    float* eh     = ws + alloc(nE);
    float* et     = ws + alloc(nE);
    float* er     = ws + alloc(nR);
    __half* Mh    = (__half*)(ws + alloc((size_t)nR * 128));   // nR*256 halves
    __half* Mt    = (__half*)(ws + alloc((size_t)nR * 128));
    size_t common_words = o;

    size_t hist_words  = 64 * 512;
    size_t part1_words = (size_t)NSUP * CAP1;
    size_t part2_words = ((size_t)NBUCK * CAP2 + 1) / 2;       // u16 -> words
    size_t new_words = hist_words + 64 + NBUCK + part1_words + part2_words;
    bool planNew = (NBLK1 <= 512) && (NSUP <= 64) &&
                   (ws_size >= (common_words + new_words + 64) * 4);

    k_scores<<<(nE + nR + 3) / 4, 256, 0, stream>>>(xe, xr, wah, wat, war, eh, et, er, nE, nR);
    k_rel<<<nR, 256, 0, stream>>>(xr, W1, b1, W2, b2, Wr, Mh, Mt);

    if (planNew) {
        int* hist   = (int*)(ws + alloc(hist_words));
        int* bcur1  = (int*)(ws + alloc(64));
        int* bcur2  = (int*)(ws + alloc(NBUCK));
        unsigned* part1 = (unsigned*)(ws + alloc(part1_words));
        unsigned short* part2 = (unsigned short*)(ws + alloc(part2_words));
        hipMemsetAsync(bcur2, 0, (size_t)NBUCK * sizeof(int), stream);
        k_hist1<<<NBLK1, 256, 0, stream>>>(ei, hist, E);
        k_scanp<<<64, 256, 0, stream>>>(hist, bcur1, NBLK1);
        k_part1<<<NBLK1, 256, 0, stream>>>(ei, rel, hist, part1, E);
        k_part2<<<NSUP * CHUNK2, 256, 0, stream>>>(bcur1, part1, bcur2, part2);
        k_group_out4<<<NBUCK, 256, 0, stream>>>(bcur2, part2, eh, et, er, Mh, Mt, br, out, nE, nR);
    } else {
        int* cursor = (int*)(ws + alloc(N));
        int* deg    = (int*)(ws + alloc(N));
        int* offs   = (int*)(ws + alloc(N));
        int* bsum   = (int*)(ws + alloc(512));
        unsigned* csr = (unsigned*)(ws + alloc(2 * (size_t)E));
        const int NB = (N + 1023) / 1024;
        hipMemsetAsync(deg, 0, (size_t)N * sizeof(int), stream);
        k_hist<<<(E + 255) / 256, 256, 0, stream>>>(ei, deg, E, nE);
        k_scan1<<<NB, 256, 0, stream>>>(deg, offs, bsum, N);
        k_scan2<<<1, 256, 0, stream>>>(bsum, NB);
        k_scan3<<<(N + 255) / 256, 256, 0, stream>>>(offs, bsum, cursor, N);
        k_scatter_offs<<<(E + 255) / 256, 256, 0, stream>>>(ei, rel, eh, et, er, cursor, csr, E, nE);
        k_out_offs<<<(nE + 3) / 4, 256, 0, stream>>>(offs, deg, csr, Mh, Mt, br, out, nE);
    }
}